// Round 15
// baseline (47.288 us; speedup 1.0000x reference)
//
#include <hip/hip_runtime.h>
#include <cstddef>

#define SB 2
#define SS 4096
#define SH 8
#define SD 64
#define SP 64          // half-window
#define SNO 129        // W+1 offsets
#define TQ 16          // query tokens per attn block
#define WN 144         // TQ + 2*SP key window
#define NT16 (SS/TQ)   // 256 tiles per batch
#define SSTR 168       // Ss row stride (f16); cols [WN,160) zero-padded for PV

typedef _Float16 f16;
typedef __attribute__((ext_vector_type(8))) _Float16 f16x8;
typedef __attribute__((ext_vector_type(4))) float floatx4;

union f16frag { f16 h[8]; ushort4 u4[2]; f16x8 v; };

__device__ __forceinline__ float fast_tanh(float x) {
  float ax = fabsf(x);
  float e = __expf(2.0f * ax);
  float t = 1.0f - 2.0f / (e + 1.0f);
  return copysignf(t, x);
}

// read 16 f32 from global, convert, store 16 f16 to LDS
__device__ __forceinline__ void cvt16(const float* __restrict__ src, f16* __restrict__ dst) {
  float4 x0 = *(const float4*)(src);
  float4 x1 = *(const float4*)(src + 4);
  float4 x2 = *(const float4*)(src + 8);
  float4 x3 = *(const float4*)(src + 12);
  f16frag a, c;
  a.h[0]=(f16)x0.x; a.h[1]=(f16)x0.y; a.h[2]=(f16)x0.z; a.h[3]=(f16)x0.w;
  a.h[4]=(f16)x1.x; a.h[5]=(f16)x1.y; a.h[6]=(f16)x1.z; a.h[7]=(f16)x1.w;
  c.h[0]=(f16)x2.x; c.h[1]=(f16)x2.y; c.h[2]=(f16)x2.z; c.h[3]=(f16)x2.w;
  c.h[4]=(f16)x3.x; c.h[5]=(f16)x3.y; c.h[6]=(f16)x3.z; c.h[7]=(f16)x3.w;
  *(ushort4*)(dst)      = a.u4[0];
  *(ushort4*)(dst + 4)  = a.u4[1];
  *(ushort4*)(dst + 8)  = c.u4[0];
  *(ushort4*)(dst + 12) = c.u4[1];
}

// ---------------- prep: project Q,K (f16 MFMA) + convert/transpose V ----------------
__global__ __launch_bounds__(256) void prep_kernel(
    const float* __restrict__ q, const float* __restrict__ k, const float* __restrict__ v,
    const float* __restrict__ Wq, const float* __restrict__ bq,
    const float* __restrict__ Wk, const float* __restrict__ bk,
    f16* __restrict__ Qf, f16* __restrict__ Kf, f16* __restrict__ Vt)
{
  __shared__ f16 sWq[64*72], sWk[64*72], sQr[64*72], sKr[64*72], sVr[64*72];
  __shared__ float sbq[64], sbk[64];

  int t = threadIdx.x;
  int blk = blockIdx.x;
  int c = blk & 63; int bh = blk >> 6; int h = bh & 7; int b = bh >> 3;
  int s0 = c * 64;

  int dr = t >> 2, e0 = (t & 3) * 16;
  cvt16(Wq + dr*64 + e0, &sWq[dr*72 + e0]);
  cvt16(Wk + dr*64 + e0, &sWk[dr*72 + e0]);
  {
    size_t rbase = ((size_t)(b*SS + s0 + dr)) * (SH*SD) + h*SD + e0;
    cvt16(q + rbase, &sQr[dr*72 + e0]);
    cvt16(k + rbase, &sKr[dr*72 + e0]);
    cvt16(v + rbase, &sVr[dr*72 + e0]);
  }
  if (t < 64) { sbq[t] = bq[t]; sbk[t] = bk[t]; }
  __syncthreads();

  int lane = t & 63, wave = t >> 6;
  int r16 = lane & 15, g = lane >> 4;

  size_t hsbase = (size_t)(b*SH + h) * SS;

  #pragma unroll
  for (int j = 0; j < 4; ++j) {
    int tt = wave + 4*j;
    int si = tt >> 2, dj = tt & 3;
    floatx4 accq = {0.f,0.f,0.f,0.f}, acck = {0.f,0.f,0.f,0.f};
    #pragma unroll
    for (int e = 0; e < 64; e += 32) {
      f16x8 aq = *(const f16x8*)&sQr[(si*16 + r16)*72 + e + g*8];
      f16x8 ak = *(const f16x8*)&sKr[(si*16 + r16)*72 + e + g*8];
      f16x8 wq8 = *(const f16x8*)&sWq[(dj*16 + r16)*72 + e + g*8];
      f16x8 wk8 = *(const f16x8*)&sWk[(dj*16 + r16)*72 + e + g*8];
      accq = __builtin_amdgcn_mfma_f32_16x16x32_f16(aq, wq8, accq, 0, 0, 0);
      acck = __builtin_amdgcn_mfma_f32_16x16x32_f16(ak, wk8, acck, 0, 0, 0);
    }
    float biasq = sbq[dj*16 + r16];
    float biask = sbk[dj*16 + r16];
    #pragma unroll
    for (int rr = 0; rr < 4; ++rr) {
      int srow = s0 + si*16 + g*4 + rr;
      Qf[(hsbase + srow)*64 + dj*16 + r16] = (f16)(accq[rr] + biasq);
      Kf[(hsbase + srow)*64 + dj*16 + r16] = (f16)(acck[rr] + biask);
    }
  }

  // V transpose: Vt[b,h,d,s]
  {
    int d = t >> 2, p4 = t & 3, sc0 = p4 * 16;
    f16frag a, c2;
    #pragma unroll
    for (int j2 = 0; j2 < 8; ++j2) a.h[j2] = sVr[(sc0 + j2)*72 + d];
    #pragma unroll
    for (int j2 = 0; j2 < 8; ++j2) c2.h[j2] = sVr[(sc0 + 8 + j2)*72 + d];
    f16* dst = Vt + ((size_t)(b*SH + h)*64 + d)*SS + s0 + sc0;
    *(ushort4*)dst       = a.u4[0];
    *(ushort4*)(dst + 4) = a.u4[1];
    *(ushort4*)(dst + 8) = c2.u4[0];
    *(ushort4*)(dst + 12)= c2.u4[1];
  }
}

// ---------------- fused attention: one block per (b,16-tile); wave = head --------
// 512 blocks x 512 threads (8 waves). Wave-private Ss slice; no barrier between
// scores and PV. sAF REMOVED (LDS 81->47 KB): af assembled post-PV directly from
// the 8 priv slices with 32B full-sector coalesced stores (no integer div).
// Barriers: stage / all-Ss / af-reads-done / dumps-done.
__global__ __launch_bounds__(512, 4) void attn_fused(
    const f16* __restrict__ Qf, const f16* __restrict__ Kf, const f16* __restrict__ Vt,
    const float* __restrict__ ocpe, float* __restrict__ af, float* __restrict__ outp)
{
  __shared__ f16 sPriv[SH][TQ*SSTR];    // 43,008 B (per-wave Ss; later f32 out-partials)
  __shared__ float sObT[SH*SNO];        // 4,128 B   [h][o]

  int t = threadIdx.x;
  int lane = t & 63, wave = t >> 6;
  int r16 = lane & 15, g = lane >> 4;

  // XCD-chunked mapping (bijective: 512 = 8*64)
  int blk = blockIdx.x;
  int G = (blk & 7) * 64 + (blk >> 3);
  int b = G >> 8, t16 = G & 255;
  int t0 = t16 * TQ, yg0 = t0 - SP;

  for (int idx = t; idx < SNO*SH; idx += 512) {
    int o = idx >> 3, h2 = idx & 7;
    sObT[h2*SNO + o] = ocpe[idx];
  }

  int h = wave;
  f16* priv = &sPriv[wave][0];
  // zero own pad cols [WN,160)
  #pragma unroll
  for (int j = 0; j < 4; ++j)
    priv[r16*SSTR + WN + g*4 + j] = (f16)0.f;

  __syncthreads();   // (1) sObT visible

  const float* ob = &sObT[h*SNO];
  const f16* qb = Qf + ((size_t)(b*SH + h)*SS + t0 + r16)*64;
  f16x8 qa0 = *(const f16x8*)(qb + g*8);
  f16x8 qa1 = *(const f16x8*)(qb + 32 + g*8);
  const f16* kbase = Kf + ((size_t)(b*SH + h)*SS)*64;

  // scores: 9 y-tiles cover y in [0,144); priv store only (no sAF duplication)
  #pragma unroll
  for (int yy = 0; yy < 9; ++yy) {
    int y = yy*16 + r16;
    int ygr = yg0 + y;
    int ygc = min(max(ygr, 0), SS-1);
    bool yok = (ygr >= 0) & (ygr < SS);
    const f16* kr = kbase + (size_t)ygc * 64;
    f16x8 kb0 = *(const f16x8*)(kr + g*8);
    f16x8 kb1 = *(const f16x8*)(kr + 32 + g*8);
    floatx4 acc = {0.f,0.f,0.f,0.f};
    acc = __builtin_amdgcn_mfma_f32_16x16x32_f16(qa0, kb0, acc, 0, 0, 0);
    acc = __builtin_amdgcn_mfma_f32_16x16x32_f16(qa1, kb1, acc, 0, 0, 0);
    #pragma unroll
    for (int rr = 0; rr < 4; ++rr) {
      int i = g*4 + rr;
      int o = y - i;
      bool ook = (o >= 0) & (o <= 2*SP);
      float a = 0.f;
      if (yok & ook) a = fast_tanh(acc[rr] + ob[o]);
      priv[i*SSTR + y] = (f16)a;
    }
  }

  // PV: own slice (no barrier; same-wave ds ordering), all 4 d-tiles
  floatx4 acc2[4] = {{0.f,0.f,0.f,0.f},{0.f,0.f,0.f,0.f},{0.f,0.f,0.f,0.f},{0.f,0.f,0.f,0.f}};
  const f16* vb0 = Vt + ((size_t)(b*SH + h)*64 + r16)*SS;
  #pragma unroll
  for (int ks = 0; ks < 5; ++ks) {
    int yb = ks*32 + g*8;
    int ygr = yg0 + yb;
    int ygc = min(max(ygr, 0), SS-8);
    f16x8 a0 = *(const f16x8*)&priv[r16*SSTR + yb];
    #pragma unroll
    for (int dq = 0; dq < 4; ++dq) {
      f16x8 bv = *(const f16x8*)(vb0 + (size_t)(dq*16)*SS + ygc);
      acc2[dq] = __builtin_amdgcn_mfma_f32_16x16x32_f16(a0, bv, acc2[dq], 0, 0, 0);
    }
  }

  __syncthreads();   // (2) ALL waves' Ss complete

  // af: assemble [i][o][0..7] from the 8 priv slices -> one 32B store per (i,o).
  // thread: i = t>>5 (0..15), o = (t&31) + 32j. Cross-slice reads: consecutive-o
  // lanes -> 2 lanes/bank (free).
  {
    int i = t >> 5, o0 = t & 31;
    int rbase = i*SSTR + i;
    float* afb = af + (((size_t)b*SS + t0 + i)*SNO)*SH;
    #pragma unroll
    for (int j = 0; j < 5; ++j) {
      int o = o0 + 32*j;
      if (o < SNO) {
        float v0[8];
        #pragma unroll
        for (int hh = 0; hh < 8; ++hh)
          v0[hh] = (float)sPriv[hh][rbase + o];
        float* dst = afb + (size_t)o*SH;
        *(float4*)dst       = make_float4(v0[0], v0[1], v0[2], v0[3]);
        *(float4*)(dst + 4) = make_float4(v0[4], v0[5], v0[6], v0[7]);
      }
    }
  }

  __syncthreads();   // (3) all af reads of every slice done

  // dump out-partial into OWN priv slice as f32 [i][d] (4096B <= 5376B slice)
  {
    float* po = (float*)priv;
    #pragma unroll
    for (int dq = 0; dq < 4; ++dq)
      #pragma unroll
      for (int rr = 0; rr < 4; ++rr)
        po[(g*4 + rr)*64 + dq*16 + r16] = acc2[dq][rr];
  }

  __syncthreads();   // (4) all dumps complete

  // out: cross-head reduce, 512 threads x float2 -> full 64B lines
  {
    int e2 = t * 2;
    int i = e2 >> 6, d = e2 & 63;
    float sx = 0.f, sy = 0.f;
    #pragma unroll
    for (int h2 = 0; h2 < SH; ++h2) {
      const float* ph = (const float*)&sPriv[h2][0];
      sx += ph[i*64 + d];
      sy += ph[i*64 + d + 1];
    }
    *(float2*)(outp + ((size_t)b*SS + t0 + i)*64 + d) = make_float2(sx, sy);
  }
}

extern "C" void kernel_launch(void* const* d_in, const int* in_sizes, int n_in,
                              void* d_out, int out_size, void* d_ws, size_t ws_size,
                              hipStream_t stream) {
  const float* q    = (const float*)d_in[0];
  const float* k    = (const float*)d_in[1];
  const float* v    = (const float*)d_in[2];
  const float* Wq   = (const float*)d_in[3];
  const float* bq   = (const float*)d_in[4];
  const float* Wk   = (const float*)d_in[5];
  const float* bk   = (const float*)d_in[6];
  const float* ocpe = (const float*)d_in[7];

  // ws: Kf (8.39MB) + Vt (8.39MB) + Qf (8.39MB) = 25.2MB (fits proven 33.7MB)
  f16* Kf = (f16*)d_ws;
  f16* Vt = Kf + (size_t)SB*SH*SS*SD;
  f16* Qf = Vt + (size_t)SB*SH*SS*SD;

  float* af = (float*)d_out;
  float* op = af + (size_t)SB*SS*SNO*SH;

  prep_kernel<<<SB*SH*64, 256, 0, stream>>>(q, k, v, Wq, bq, Wk, bk, Qf, Kf, Vt);
  attn_fused<<<SB*NT16, 512, 0, stream>>>(Qf, Kf, Vt, ocpe, af, op);
}

// Round 16
// 44.590 us; speedup vs baseline: 1.0605x; 1.0605x over previous
//
#include <hip/hip_runtime.h>
#include <cstddef>

#define SB 2
#define SS 4096
#define SH 8
#define SD 64
#define SP 64          // half-window
#define SNO 129        // W+1 offsets
#define TQ 16          // query tokens per attn block
#define WN 144         // TQ + 2*SP key window
#define NT16 (SS/TQ)   // 256 tiles per batch
#define SSTR 168       // Ss row stride (f16); cols [WN,160) zero-padded for PV

typedef _Float16 f16;
typedef __attribute__((ext_vector_type(8))) _Float16 f16x8;
typedef __attribute__((ext_vector_type(4))) float floatx4;

union f16frag { f16 h[8]; ushort4 u4[2]; f16x8 v; };

__device__ __forceinline__ float fast_tanh(float x) {
  float ax = fabsf(x);
  float e = __expf(2.0f * ax);
  float t = 1.0f - 2.0f / (e + 1.0f);
  return copysignf(t, x);
}

// read 16 f32 from global, convert, store 16 f16 to LDS
__device__ __forceinline__ void cvt16(const float* __restrict__ src, f16* __restrict__ dst) {
  float4 x0 = *(const float4*)(src);
  float4 x1 = *(const float4*)(src + 4);
  float4 x2 = *(const float4*)(src + 8);
  float4 x3 = *(const float4*)(src + 12);
  f16frag a, c;
  a.h[0]=(f16)x0.x; a.h[1]=(f16)x0.y; a.h[2]=(f16)x0.z; a.h[3]=(f16)x0.w;
  a.h[4]=(f16)x1.x; a.h[5]=(f16)x1.y; a.h[6]=(f16)x1.z; a.h[7]=(f16)x1.w;
  c.h[0]=(f16)x2.x; c.h[1]=(f16)x2.y; c.h[2]=(f16)x2.z; c.h[3]=(f16)x2.w;
  c.h[4]=(f16)x3.x; c.h[5]=(f16)x3.y; c.h[6]=(f16)x3.z; c.h[7]=(f16)x3.w;
  *(ushort4*)(dst)      = a.u4[0];
  *(ushort4*)(dst + 4)  = a.u4[1];
  *(ushort4*)(dst + 8)  = c.u4[0];
  *(ushort4*)(dst + 12) = c.u4[1];
}

// ---------------- prep: project Q,K (f16 MFMA) + convert/transpose V ----------------
__global__ __launch_bounds__(256) void prep_kernel(
    const float* __restrict__ q, const float* __restrict__ k, const float* __restrict__ v,
    const float* __restrict__ Wq, const float* __restrict__ bq,
    const float* __restrict__ Wk, const float* __restrict__ bk,
    f16* __restrict__ Qf, f16* __restrict__ Kf, f16* __restrict__ Vt)
{
  __shared__ f16 sWq[64*72], sWk[64*72], sQr[64*72], sKr[64*72], sVr[64*72];
  __shared__ float sbq[64], sbk[64];

  int t = threadIdx.x;
  int blk = blockIdx.x;
  int c = blk & 63; int bh = blk >> 6; int h = bh & 7; int b = bh >> 3;
  int s0 = c * 64;

  int dr = t >> 2, e0 = (t & 3) * 16;
  cvt16(Wq + dr*64 + e0, &sWq[dr*72 + e0]);
  cvt16(Wk + dr*64 + e0, &sWk[dr*72 + e0]);
  {
    size_t rbase = ((size_t)(b*SS + s0 + dr)) * (SH*SD) + h*SD + e0;
    cvt16(q + rbase, &sQr[dr*72 + e0]);
    cvt16(k + rbase, &sKr[dr*72 + e0]);
    cvt16(v + rbase, &sVr[dr*72 + e0]);
  }
  if (t < 64) { sbq[t] = bq[t]; sbk[t] = bk[t]; }
  __syncthreads();

  int lane = t & 63, wave = t >> 6;
  int r16 = lane & 15, g = lane >> 4;

  size_t hsbase = (size_t)(b*SH + h) * SS;

  #pragma unroll
  for (int j = 0; j < 4; ++j) {
    int tt = wave + 4*j;
    int si = tt >> 2, dj = tt & 3;
    floatx4 accq = {0.f,0.f,0.f,0.f}, acck = {0.f,0.f,0.f,0.f};
    #pragma unroll
    for (int e = 0; e < 64; e += 32) {
      f16x8 aq = *(const f16x8*)&sQr[(si*16 + r16)*72 + e + g*8];
      f16x8 ak = *(const f16x8*)&sKr[(si*16 + r16)*72 + e + g*8];
      f16x8 wq8 = *(const f16x8*)&sWq[(dj*16 + r16)*72 + e + g*8];
      f16x8 wk8 = *(const f16x8*)&sWk[(dj*16 + r16)*72 + e + g*8];
      accq = __builtin_amdgcn_mfma_f32_16x16x32_f16(aq, wq8, accq, 0, 0, 0);
      acck = __builtin_amdgcn_mfma_f32_16x16x32_f16(ak, wk8, acck, 0, 0, 0);
    }
    float biasq = sbq[dj*16 + r16];
    float biask = sbk[dj*16 + r16];
    #pragma unroll
    for (int rr = 0; rr < 4; ++rr) {
      int srow = s0 + si*16 + g*4 + rr;
      Qf[(hsbase + srow)*64 + dj*16 + r16] = (f16)(accq[rr] + biasq);
      Kf[(hsbase + srow)*64 + dj*16 + r16] = (f16)(acck[rr] + biask);
    }
  }

  // V transpose: Vt[b,h,d,s]
  {
    int d = t >> 2, p4 = t & 3, sc0 = p4 * 16;
    f16frag a, c2;
    #pragma unroll
    for (int j2 = 0; j2 < 8; ++j2) a.h[j2] = sVr[(sc0 + j2)*72 + d];
    #pragma unroll
    for (int j2 = 0; j2 < 8; ++j2) c2.h[j2] = sVr[(sc0 + 8 + j2)*72 + d];
    f16* dst = Vt + ((size_t)(b*SH + h)*64 + d)*SS + s0 + sc0;
    *(ushort4*)dst       = a.u4[0];
    *(ushort4*)(dst + 4) = a.u4[1];
    *(ushort4*)(dst + 8) = c2.u4[0];
    *(ushort4*)(dst + 12)= c2.u4[1];
  }
}

// ---------------- fused attention: one block per (b,16-tile); wave = head --------
// 512 blocks x 512 threads (8 waves). R14 structure (measured best), plus:
// block-uniform INTERIOR fast path (4<=t16<=250): K/V addresses are linear
// (no per-load clamp chains) so loads issue back-to-back -> high MLP; yok
// mask constant-true. Boundary tiles use the R14 clamped path verbatim.
__global__ __launch_bounds__(512, 4) void attn_fused(
    const f16* __restrict__ Qf, const f16* __restrict__ Kf, const f16* __restrict__ Vt,
    const float* __restrict__ ocpe, float* __restrict__ af, float* __restrict__ outp)
{
  __shared__ f16 sPriv[SH][TQ*SSTR];    // 43,008 B (per-wave Ss; later f32 out-partials)
  __shared__ f16 sAF[TQ*SNO*SH];        // 33,024 B  [i][o][h]
  __shared__ float sObT[SH*SNO];        // 4,128 B   [h][o]

  int t = threadIdx.x;
  int lane = t & 63, wave = t >> 6;
  int r16 = lane & 15, g = lane >> 4;

  // XCD-chunked mapping (bijective: 512 = 8*64)
  int blk = blockIdx.x;
  int G = (blk & 7) * 64 + (blk >> 3);
  int b = G >> 8, t16 = G & 255;
  int t0 = t16 * TQ, yg0 = t0 - SP;

  int h = wave;
  // ---- Q prefetch: issued before the barrier; completes under staging ----
  const f16* qb = Qf + ((size_t)(b*SH + h)*SS + t0 + r16)*64;
  f16x8 qa0 = *(const f16x8*)(qb + g*8);
  f16x8 qa1 = *(const f16x8*)(qb + 32 + g*8);

  for (int idx = t; idx < SNO*SH; idx += 512) {
    int o = idx >> 3, h2 = idx & 7;
    sObT[h2*SNO + o] = ocpe[idx];
  }

  f16* priv = &sPriv[wave][0];
  // zero own pad cols [WN,160)
  #pragma unroll
  for (int j = 0; j < 4; ++j)
    priv[r16*SSTR + WN + g*4 + j] = (f16)0.f;

  __syncthreads();   // sObT visible

  const float* ob = &sObT[h*SNO];
  const f16* kbase = Kf + ((size_t)(b*SH + h)*SS)*64;
  floatx4 acc2[4] = {{0.f,0.f,0.f,0.f},{0.f,0.f,0.f,0.f},{0.f,0.f,0.f,0.f},{0.f,0.f,0.f,0.f}};

  bool interior = (t16 >= 4) & (t16 <= 250);   // block-uniform

  if (interior) {
    // ---------- fast path: linear addresses, no clamps, yok == true ----------
    const f16* krow = kbase + (size_t)(yg0 + r16) * 64 + g*8;
    #pragma unroll
    for (int yy = 0; yy < 9; ++yy) {
      f16x8 kb0 = *(const f16x8*)(krow + yy*1024);
      f16x8 kb1 = *(const f16x8*)(krow + yy*1024 + 32);
      floatx4 acc = {0.f,0.f,0.f,0.f};
      acc = __builtin_amdgcn_mfma_f32_16x16x32_f16(qa0, kb0, acc, 0, 0, 0);
      acc = __builtin_amdgcn_mfma_f32_16x16x32_f16(qa1, kb1, acc, 0, 0, 0);
      int y = yy*16 + r16;
      #pragma unroll
      for (int rr = 0; rr < 4; ++rr) {
        int i = g*4 + rr;
        int o = y - i;
        bool ook = (o >= 0) & (o <= 2*SP);
        float a = 0.f;
        if (ook) a = fast_tanh(acc[rr] + ob[o]);
        priv[i*SSTR + y] = (f16)a;
        if (ook) sAF[((size_t)i*SNO + o)*SH + h] = (f16)a;
      }
    }
    // PV: linear V addresses
    const f16* vrow = Vt + ((size_t)(b*SH + h)*64 + r16)*SS + yg0 + g*8;
    #pragma unroll
    for (int ks = 0; ks < 5; ++ks) {
      int yb = ks*32 + g*8;
      f16x8 a0 = *(const f16x8*)&priv[r16*SSTR + yb];
      #pragma unroll
      for (int dq = 0; dq < 4; ++dq) {
        f16x8 bv = *(const f16x8*)(vrow + (size_t)(dq*16)*SS + ks*32);
        acc2[dq] = __builtin_amdgcn_mfma_f32_16x16x32_f16(a0, bv, acc2[dq], 0, 0, 0);
      }
    }
  } else {
    // ---------- boundary path: R14 clamped code verbatim ----------
    #pragma unroll
    for (int yy = 0; yy < 9; ++yy) {
      int y = yy*16 + r16;
      int ygr = yg0 + y;
      int ygc = min(max(ygr, 0), SS-1);
      bool yok = (ygr >= 0) & (ygr < SS);
      const f16* kr = kbase + (size_t)ygc * 64;
      f16x8 kb0 = *(const f16x8*)(kr + g*8);
      f16x8 kb1 = *(const f16x8*)(kr + 32 + g*8);
      floatx4 acc = {0.f,0.f,0.f,0.f};
      acc = __builtin_amdgcn_mfma_f32_16x16x32_f16(qa0, kb0, acc, 0, 0, 0);
      acc = __builtin_amdgcn_mfma_f32_16x16x32_f16(qa1, kb1, acc, 0, 0, 0);
      #pragma unroll
      for (int rr = 0; rr < 4; ++rr) {
        int i = g*4 + rr;
        int o = y - i;
        bool ook = (o >= 0) & (o <= 2*SP);
        float a = 0.f;
        if (yok & ook) a = fast_tanh(acc[rr] + ob[o]);
        priv[i*SSTR + y] = (f16)a;
        if (ook) sAF[((size_t)i*SNO + o)*SH + h] = (f16)a;
      }
    }
    const f16* vb0 = Vt + ((size_t)(b*SH + h)*64 + r16)*SS;
    #pragma unroll
    for (int ks = 0; ks < 5; ++ks) {
      int yb = ks*32 + g*8;
      int ygr = yg0 + yb;
      int ygc = min(max(ygr, 0), SS-8);
      f16x8 a0 = *(const f16x8*)&priv[r16*SSTR + yb];
      #pragma unroll
      for (int dq = 0; dq < 4; ++dq) {
        f16x8 bv = *(const f16x8*)(vb0 + (size_t)(dq*16)*SS + ygc);
        acc2[dq] = __builtin_amdgcn_mfma_f32_16x16x32_f16(a0, bv, acc2[dq], 0, 0, 0);
      }
    }
  }

  // dump out-partial into OWN priv slice as f32 [i][d] (4096B <= 5376B slice)
  {
    float* po = (float*)priv;
    #pragma unroll
    for (int dq = 0; dq < 4; ++dq)
      #pragma unroll
      for (int rr = 0; rr < 4; ++rr)
        po[(g*4 + rr)*64 + dq*16 + r16] = acc2[dq][rr];
  }

  __syncthreads();   // all waves' priv out-partials + sAF complete

  // out: cross-head reduce, 512 threads x float2 -> full 64B lines
  {
    int e2 = t * 2;
    int i = e2 >> 6, d = e2 & 63;
    float sx = 0.f, sy = 0.f;
    #pragma unroll
    for (int h2 = 0; h2 < SH; ++h2) {
      const float* ph = (const float*)&sPriv[h2][0];
      sx += ph[i*64 + d];
      sy += ph[i*64 + d + 1];
    }
    *(float2*)(outp + ((size_t)b*SS + t0 + i)*64 + d) = make_float2(sx, sy);
  }

  // af: flat f16 -> f32 streaming copy (full lines)
  {
    float* afb = af + ((size_t)b*SS + t0) * (size_t)(SNO*SH);
    for (int idx = t; idx < TQ*SNO*SH/4; idx += 512) {
      const f16* s = &sAF[idx*4];
      float4 w = make_float4((float)s[0], (float)s[1], (float)s[2], (float)s[3]);
      *(float4*)(afb + idx*4) = w;
    }
  }
}

extern "C" void kernel_launch(void* const* d_in, const int* in_sizes, int n_in,
                              void* d_out, int out_size, void* d_ws, size_t ws_size,
                              hipStream_t stream) {
  const float* q    = (const float*)d_in[0];
  const float* k    = (const float*)d_in[1];
  const float* v    = (const float*)d_in[2];
  const float* Wq   = (const float*)d_in[3];
  const float* bq   = (const float*)d_in[4];
  const float* Wk   = (const float*)d_in[5];
  const float* bk   = (const float*)d_in[6];
  const float* ocpe = (const float*)d_in[7];

  // ws: Kf (8.39MB) + Vt (8.39MB) + Qf (8.39MB) = 25.2MB (fits proven 33.7MB)
  f16* Kf = (f16*)d_ws;
  f16* Vt = Kf + (size_t)SB*SH*SS*SD;
  f16* Qf = Vt + (size_t)SB*SH*SS*SD;

  float* af = (float*)d_out;
  float* op = af + (size_t)SB*SS*SNO*SH;

  prep_kernel<<<SB*SH*64, 256, 0, stream>>>(q, k, v, Wq, bq, Wk, bk, Qf, Kf, Vt);
  attn_fused<<<SB*NT16, 512, 0, stream>>>(Qf, Kf, Vt, ocpe, af, op);
}